// Round 4
// baseline (1134.709 us; speedup 1.0000x reference)
//
#include <hip/hip_runtime.h>
#include <hip/hip_bf16.h>

#define TSTEPS 2048
#define NB 64
#define DH 256
#define NBDH (NB * DH)

typedef __attribute__((ext_vector_type(8))) short short8;
typedef __attribute__((ext_vector_type(4))) float f32x4;

__device__ __forceinline__ unsigned short f2bf(float f) {
  union { float f; unsigned u; } v; v.f = f;
  unsigned u = v.u;
  u += 0x7FFFu + ((u >> 16) & 1u);   // round-to-nearest-even
  return (unsigned short)(u >> 16);
}

__device__ __forceinline__ float fast_tanh(float x) {
  // tanh(x) = 1 - 2/(e^{2x}+1); saturates correctly at +/-1
  float e = __builtin_amdgcn_exp2f(x * 2.885390081777927f);  // e^{2x}
  return 1.0f - 2.0f * __builtin_amdgcn_rcpf(e + 1.0f);
}

// permuted hidden index: LDS/hs position p <-> original column c
// p = g*32 + 2*j + half  <->  c = g*32 + half*16 + j
__device__ __forceinline__ int p2c(int p) {
  int q = p & 31;
  return (p & ~31) | ((q & 1) << 4) | (q >> 1);
}

// ---- kernel 0: f32 -> bf16 weights; W_hid/W_out get k-dim permuted ----
__global__ void cvt_w(const float* __restrict__ a, const float* __restrict__ b,
                      const float* __restrict__ c, unsigned short* __restrict__ dst) {
  int i = blockIdx.x * 256 + threadIdx.x;  // 0 .. 3*65536-1
  int mat = i >> 16, idx = i & 65535;
  float s;
  if (mat == 0) {
    s = a[idx];                            // W_in: unpermuted
  } else {
    int n = idx >> 8, p = idx & 255;
    const float* m = (mat == 1) ? b : c;
    s = m[n * 256 + p2c(p)];
  }
  dst[i] = f2bf(s);
}

// ---- kernels 1 & 3: C[M,256] = A[M,256] * W[256,256]^T  (W row-major [n][k], bf16)
template <bool A_BF16>
__global__ __launch_bounds__(256) void gemm_nt(
    const void* __restrict__ Aptr, const unsigned short* __restrict__ Wbf,
    float* __restrict__ Cout) {
  const int w = threadIdx.x >> 6, l = threadIdx.x & 63;
  const int m16 = l & 15, kg = l >> 4;
  const long tile0 = ((long)blockIdx.x * 4 + w) * 2;

  short8 afr[2][8];
  for (int ti = 0; ti < 2; ++ti) {
    long row = (tile0 + ti) * 16 + m16;
    if (A_BF16) {
      const unsigned short* ar = (const unsigned short*)Aptr + row * 256 + kg * 8;
      for (int ks = 0; ks < 8; ++ks) afr[ti][ks] = *(const short8*)(ar + ks * 32);
    } else {
      const float* ar = (const float*)Aptr + row * 256 + kg * 8;
      for (int ks = 0; ks < 8; ++ks) {
        const float4* p = (const float4*)(ar + ks * 32);
        float4 f0 = p[0], f1 = p[1];
        short8 s;
        s[0] = (short)f2bf(f0.x); s[1] = (short)f2bf(f0.y);
        s[2] = (short)f2bf(f0.z); s[3] = (short)f2bf(f0.w);
        s[4] = (short)f2bf(f1.x); s[5] = (short)f2bf(f1.y);
        s[6] = (short)f2bf(f1.z); s[7] = (short)f2bf(f1.w);
        afr[ti][ks] = s;
      }
    }
  }
  for (int nt = 0; nt < 16; ++nt) {
    const int n = nt * 16 + m16;
    const unsigned short* wr = Wbf + n * 256 + kg * 8;
    f32x4 acc0 = {0.f, 0.f, 0.f, 0.f}, acc1 = {0.f, 0.f, 0.f, 0.f};
    for (int ks = 0; ks < 8; ++ks) {
      short8 b = *(const short8*)(wr + ks * 32);
      acc0 = __builtin_amdgcn_mfma_f32_16x16x32_bf16(afr[0][ks], b, acc0, 0, 0, 0);
      acc1 = __builtin_amdgcn_mfma_f32_16x16x32_bf16(afr[1][ks], b, acc1, 0, 0, 0);
    }
    for (int r = 0; r < 4; ++r) {
      Cout[(tile0 * 16 + kg * 4 + r) * 256 + n]       = acc0[r];
      Cout[((tile0 + 1) * 16 + kg * 4 + r) * 256 + n] = acc1[r];
    }
  }
}

// ---- kernel 2: sequential scan. 64 blocks x 1 batch row, 8 waves x 32 cols.
// h lives in LDS in PERMUTED order p (matches pre-permuted W_hid k-dim), so a
// lane's two outputs (orig cols w*32+j, w*32+16+j) pack into one u32 via
// v_cvt_pk_bf16_f32 at u16-pos w*32+2j. 8 independent MFMA chains of depth 2.
__global__ __launch_bounds__(512, 2) void rnn_scan(
    const float* __restrict__ xp, const unsigned short* __restrict__ Wbf,
    const float* __restrict__ h0, unsigned short* __restrict__ hs) {
  __shared__ unsigned short hA[2][256];
  const int tid = threadIdx.x, w = tid >> 6, l = tid & 63;
  const int b = blockIdx.x;           // one batch row per block
  const int m16 = l & 15, kg = l >> 4;

  // W_hid B-fragments resident (k pre-permuted): wave owns orig cols [w*32, w*32+32)
  short8 bf0[8], bf1[8];
  {
    const unsigned short* wr0 = Wbf + (w * 32 + m16) * 256 + kg * 8;
    const unsigned short* wr1 = Wbf + (w * 32 + 16 + m16) * 256 + kg * 8;
    for (int ks = 0; ks < 8; ++ks) {
      bf0[ks] = *(const short8*)(wr0 + ks * 32);
      bf1[ks] = *(const short8*)(wr1 + ks * 32);
    }
  }

  if (tid < 256) hA[0][tid] = f2bf(h0[b * 256 + p2c(tid)]);
  __syncthreads();

  const int col0 = w * 32 + m16;                       // orig col of output v0
  const unsigned short* rdp = &hA[0][0] + kg * 8;      // + CUR*256 + ks*32 (imm)
  const float* xpb = xp + (long)b * 256 + col0;        // + t*NBDH
  unsigned* hsw = (unsigned*)(hs + (long)b * 256 + w * 32 + 2 * m16);  // + t*8192
  unsigned* lds_w0 = (unsigned*)&hA[0][0] + (w * 16 + m16);
  unsigned* lds_w1 = (unsigned*)&hA[1][0] + (w * 16 + m16);

  // 4-deep xp prefetch rotation
  float xv0[2], xv1[2], xv2[2], xv3[2];
  if (l < 16) {
    xv0[0] = xpb[0];               xv0[1] = xpb[16];
    xv1[0] = xpb[1L * NBDH];       xv1[1] = xpb[1L * NBDH + 16];
    xv2[0] = xpb[2L * NBDH];       xv2[1] = xpb[2L * NBDH + 16];
    xv3[0] = xpb[3L * NBDH];       xv3[1] = xpb[3L * NBDH + 16];
  }

#define M16 __builtin_amdgcn_mfma_f32_16x16x32_bf16
#define RNN_STEP(T, CUR, XV, PF)                                              \
  {                                                                           \
    const short8* ap = (const short8*)(rdp + (CUR) * 256);                    \
    short8 a0 = ap[0],  a1 = ap[4],  a2 = ap[8],  a3 = ap[12];                \
    short8 a4 = ap[16], a5 = ap[20], a6 = ap[24], a7 = ap[28];                \
    f32x4 cA, cB, cC, cD, cE, cF, cG, cH;  /* elems 1..3 never read */        \
    cA[0] = XV[0]; cB[0] = 0.f; cC[0] = 0.f; cD[0] = 0.f;                     \
    cE[0] = XV[1]; cF[0] = 0.f; cG[0] = 0.f; cH[0] = 0.f;                     \
    if ((PF) && l < 16) {                                                     \
      const float* q = xpb + (long)((T) + 4) * NBDH;                          \
      XV[0] = q[0]; XV[1] = q[16];                                            \
    }                                                                         \
    cA = M16(a0, bf0[0], cA, 0, 0, 0); cE = M16(a0, bf1[0], cE, 0, 0, 0);     \
    cB = M16(a2, bf0[2], cB, 0, 0, 0); cF = M16(a2, bf1[2], cF, 0, 0, 0);     \
    cC = M16(a4, bf0[4], cC, 0, 0, 0); cG = M16(a4, bf1[4], cG, 0, 0, 0);     \
    cD = M16(a6, bf0[6], cD, 0, 0, 0); cH = M16(a6, bf1[6], cH, 0, 0, 0);     \
    cA = M16(a1, bf0[1], cA, 0, 0, 0); cE = M16(a1, bf1[1], cE, 0, 0, 0);     \
    cB = M16(a3, bf0[3], cB, 0, 0, 0); cF = M16(a3, bf1[3], cF, 0, 0, 0);     \
    cC = M16(a5, bf0[5], cC, 0, 0, 0); cG = M16(a5, bf1[5], cG, 0, 0, 0);     \
    cD = M16(a7, bf0[7], cD, 0, 0, 0); cH = M16(a7, bf1[7], cH, 0, 0, 0);     \
    float s0 = (cA[0] + cB[0]) + (cC[0] + cD[0]);                             \
    float s1 = (cE[0] + cF[0]) + (cG[0] + cH[0]);                             \
    float t0 = fast_tanh(s0), t1 = fast_tanh(s1);                             \
    unsigned pk;                                                              \
    asm("v_cvt_pk_bf16_f32 %0, %1, %2" : "=v"(pk) : "v"(t0), "v"(t1));        \
    if (l < 16) {                                                             \
      *((CUR) ? lds_w0 : lds_w1) = pk;                                        \
      hsw[(long)(T) * 8192] = pk;                                             \
    }                                                                         \
    asm volatile("s_waitcnt lgkmcnt(0)" ::: "memory");  /* LDS drain only */  \
    __builtin_amdgcn_s_barrier();                                             \
    __builtin_amdgcn_sched_barrier(0);                                        \
  }

#pragma unroll 1
  for (int t = 0; t < TSTEPS - 4; t += 4) {
    RNN_STEP(t, 0, xv0, true);
    RNN_STEP(t + 1, 1, xv1, true);
    RNN_STEP(t + 2, 0, xv2, true);
    RNN_STEP(t + 3, 1, xv3, true);
  }
  RNN_STEP(TSTEPS - 4, 0, xv0, false);
  RNN_STEP(TSTEPS - 3, 1, xv1, false);
  RNN_STEP(TSTEPS - 2, 0, xv2, false);
  RNN_STEP(TSTEPS - 1, 1, xv3, false);
#undef RNN_STEP
#undef M16
}

// ---- kernel 4: h_last[b][c] = f32(hs[T-1][b][p]), un-permuting columns
__global__ void hlast_k(const unsigned short* __restrict__ hs, float* __restrict__ hlast) {
  int i = blockIdx.x * 1024 + threadIdx.x;          // 16 blocks x 1024 = 16384
  int b = i >> 8, p = i & 255;
  unsigned u = (unsigned)hs[(long)(TSTEPS - 1) * NBDH + b * 256 + p] << 16;
  union { unsigned u; float f; } v; v.u = u;
  hlast[b * 256 + p2c(p)] = v.f;
}

extern "C" void kernel_launch(void* const* d_in, const int* in_sizes, int n_in,
                              void* d_out, int out_size, void* d_ws, size_t ws_size,
                              hipStream_t stream) {
  const float* x    = (const float*)d_in[0];
  const float* h0   = (const float*)d_in[1];
  const float* Win  = (const float*)d_in[2];
  const float* Whid = (const float*)d_in[3];
  const float* Wout = (const float*)d_in[4];
  float* ys    = (float*)d_out;
  float* hlast = ys + (long)TSTEPS * NB * 256;

  // d_ws layout: [bf16 W_in | bf16 Wp_hid | bf16 Wp_out | f32 xp (128MB) | bf16 hs (64MB)]
  unsigned short* wbf     = (unsigned short*)d_ws;
  unsigned short* wbf_in  = wbf;
  unsigned short* wbf_hid = wbf + 65536;
  unsigned short* wbf_out = wbf + 131072;
  float* xproj = (float*)((char*)d_ws + 393216);
  unsigned short* hsbuf =
      (unsigned short*)((char*)d_ws + 393216 + (size_t)TSTEPS * NB * 256 * 4);

  cvt_w<<<dim3(768), dim3(256), 0, stream>>>(Win, Whid, Wout, wbf);
  gemm_nt<false><<<dim3(1024), dim3(256), 0, stream>>>((const void*)x, wbf_in, xproj);
  rnn_scan<<<dim3(64), dim3(512), 0, stream>>>(xproj, wbf_hid, h0, hsbuf);
  gemm_nt<true><<<dim3(1024), dim3(256), 0, stream>>>((const void*)hsbuf, wbf_out, ys);
  hlast_k<<<dim3(16), dim3(1024), 0, stream>>>(hsbuf, hlast);
}